// Round 2
// baseline (273.964 us; speedup 1.0000x reference)
//
#include <hip/hip_runtime.h>
#include <hip/hip_bf16.h>

typedef unsigned short u16;
typedef short s8v __attribute__((ext_vector_type(8)));
typedef float f4v __attribute__((ext_vector_type(4)));

#define F 128
#define CIN 1024
#define CMID 512
#define XP 130
#define K9 9216

// gemm LDS element offsets (u16 units)
#define A_ELEMS 8704           // 136 rows * 64
#define B_ELEMS 8192           // 128 rows * 64
#define AOFF(b) ((b) * A_ELEMS)
#define BOFF(b) (2 * A_ELEMS + (b) * B_ELEMS)

__device__ __forceinline__ u16 f2bf(float v) {
    union { float f; unsigned u; } x; x.f = v;
    unsigned r = x.u + 0x7fff + ((x.u >> 16) & 1);
    return (u16)(r >> 16);
}
__device__ __forceinline__ float bf2f(u16 u) {
    union { unsigned u; float f; } x; x.u = ((unsigned)u) << 16; return x.f;
}

__device__ __forceinline__ void gl16(const u16* g, u16* l) {
    __builtin_amdgcn_global_load_lds(
        (const __attribute__((address_space(1))) void*)g,
        (__attribute__((address_space(3))) void*)l,
        16, 0, 0);
}

// anchor base sizes: ratios {0.5,1,2} x scales {8,16,32}
__constant__ float WBASE[9] = {184.f, 368.f, 736.f, 128.f, 256.f, 512.f,  88.f, 176.f, 352.f};
__constant__ float HBASE[9] = { 96.f, 192.f, 384.f, 128.f, 256.f, 512.f, 176.f, 352.f, 704.f};

// ---------------- fused prep ------------------------------------------------
// blocks [0,512): transpose (h, c-quarter); [512,1024): wt; [1024,1282): border;
// [1282,1410): wc
__global__ __launch_bounds__(256) void prep_all(
    const float* __restrict__ x, const float* __restrict__ bw,
    const float* __restrict__ cls_w, const float* __restrict__ reg_w,
    u16* __restrict__ xpad, u16* __restrict__ wt, u16* __restrict__ wc) {
    __shared__ char ldsraw[128 * 65 * 4];   // 33280 B (wt needs 18594)
    const int b = blockIdx.x;
    const int tid = threadIdx.x;

    if (b < 512) {                       // ---- x transpose+pad, fat blocks
        float (*lds)[65] = (float(*)[65])ldsraw;   // [w][c] per 64-c chunk
        const int h  = b >> 2;
        const int c0 = (b & 3) * 256;
        #pragma unroll 1
        for (int cc = 0; cc < 4; ++cc) {
            const int cb = c0 + cc * 64;
            {   // read: 512B-contiguous f4v per half-wave, scatter to [w][c]
                const int w4 = (tid & 31) * 4;
                const int cl = tid >> 5;         // 0..7
                #pragma unroll
                for (int p = 0; p < 8; ++p) {
                    const int c = p * 8 + cl;
                    f4v v = *(const f4v*)&x[(cb + c) * (F * F) + h * F + w4];
                    #pragma unroll
                    for (int k = 0; k < 4; ++k) lds[w4 + k][c] = v[k];
                }
            }
            __syncthreads();
            {   // write: 8 scalar LDS reads (2-way, free) -> s8v store
                const int cs = (tid & 7) * 8;
                const int wb = tid >> 3;         // 0..31
                #pragma unroll
                for (int p = 0; p < 4; ++p) {
                    const int w = p * 32 + wb;
                    s8v v;
                    #pragma unroll
                    for (int j = 0; j < 8; ++j) v[j] = (short)f2bf(lds[w][cs + j]);
                    *(s8v*)&xpad[((h + 1) * XP + (w + 1)) * CIN + cb + cs] = v;
                }
            }
            __syncthreads();
        }
    } else if (b < 1024) {               // ---- base_w OIHW -> [oc][dydx][c]
        u16* lds = (u16*)ldsraw;         // stride 1033 breaks bank conflicts
        const int oc = b - 512;
        for (int k = 0; k < 36; ++k) {
            int idx = k * 256 + tid;     // (c,dydx) linear, c-major
            float v = bw[oc * K9 + idx];
            int c = idx / 9, q = idx - c * 9;
            lds[q * 1033 + c] = f2bf(v);
        }
        __syncthreads();
        for (int k = 0; k < 36; ++k) {
            int idx = k * 256 + tid;
            int q = idx >> 10, c = idx & 1023;
            wt[oc * K9 + idx] = lds[q * 1033 + c];
        }
    } else if (b < 1282) {               // ---- border zero (vectorized)
        int t = (b - 1024) * 256 + tid;  // 516*128 chunks of 8 u16
        int cell = t >> 7, c8 = (t & 127) * 8;
        int h, w;
        if (cell < 130)      { h = 0;   w = cell; }
        else if (cell < 260) { h = 129; w = cell - 130; }
        else { int rm = cell - 260; h = 1 + (rm >> 1); w = (rm & 1) * 129; }
        s8v z = {};
        *(s8v*)&xpad[(h * XP + w) * CIN + c8] = z;
    } else {                             // ---- combined 1x1 weights
        int t = (b - 1282) * 256 + tid;  // 64*512
        int oc = t >> 9, c = t & 511;
        float v = 0.f;
        if (oc < 18)      v = cls_w[oc * 512 + c];
        else if (oc < 54) v = reg_w[(oc - 18) * 512 + c];
        wc[t] = f2bf(v);
    }
}

// ---------------- stage 1: implicit-GEMM 3x3 conv + bias + ReLU ------------
// R7 geometry (64x64 waves, 2 blocks/CU) + counted-vmcnt raw barriers:
// phase-t loads stay in flight across the barrier (land by t+1's barrier1).
// Per-wave outstanding budget: steady state = B_next(4) + A_next(5|4).
__global__ __launch_bounds__(256, 2) void gemm_conv(
    const u16* __restrict__ xpad, const u16* __restrict__ wt,
    const float* __restrict__ bias, u16* __restrict__ rpn) {
    __shared__ u16 smem[2 * A_ELEMS + 2 * B_ELEMS];   // 67584 B
    const int tid = threadIdx.x;
    const int bid = blockIdx.x;
    const int oc0 = ((bid & 7) >> 1) * 128;
    const int gh  = (bid >> 3) * 2 + (bid & 1);

    const int lane = tid & 63;
    const int wv = tid >> 6;
    const int lm = lane & 15;
    const int lq = lane >> 4;
    const int wm = (wv >> 1) * 64;
    const int wn = (wv & 1) * 64;

    // source-side XOR swizzle: lane L stages data seg (L&7)^((L>>3)&7) of its row
    const int sw = (lane & 7) ^ ((lane >> 3) & 7);
    const u16* pA = xpad + (lane >> 3) * CIN + sw * 8;
    const u16* pB = wt + (size_t)(oc0 + wv * 32 + (lane >> 3)) * K9 + sw * 8;

    f4v acc[4][4] = {};

    auto issueA = [&](int ms) {
        const int dy = ms >> 4, cc = ms & 15;
        const u16* src = pA + ((gh + dy) * XP) * CIN + cc * 64;
        u16* dst = &smem[AOFF(ms & 1)];
        #pragma unroll
        for (int jj = 0; jj < 4; ++jj) {
            const int ci = wv * 4 + jj;
            gl16(src + ci * 8 * CIN, dst + ci * 512);
        }
        if (wv == 0) gl16(src + 16 * 8 * CIN, dst + 16 * 512);  // rows 128..135
    };
    auto issueB = [&](int ms, int dx, int buf) {
        const int dy = ms >> 4, cc = ms & 15;
        const int dydx = dy * 3 + dx;
        const u16* src = pB + dydx * CIN + cc * 64;
        u16* dst = &smem[BOFF(buf) + wv * 32 * 64];
        #pragma unroll
        for (int jj = 0; jj < 4; ++jj)
            gl16(src + jj * 8 * K9, dst + jj * 8 * 64);
    };

    issueA(0);
    issueB(0, 0, 0);
    __syncthreads();   // prologue: full drain once

    int t = 0;
    for (int ms = 0; ms < 48; ++ms) {
        #pragma unroll 1
        for (int dx = 0; dx < 3; ++dx, ++t) {
            // ---- issue next-phase staging (stays in flight across barrier1)
            if (t + 1 < 144) {
                const int msn = (dx == 2) ? ms + 1 : ms;
                const int dxn = (dx == 2) ? 0 : dx + 1;
                issueB(msn, dxn, (t + 1) & 1);
            }
            if (dx == 0 && ms + 1 < 48) issueA(ms + 1);

            // ---- barrier1: counted vmcnt — all OLDER loads landed, this
            // phase's issues (<=9) still in flight.
            if (t < 141) {
                if (wv == 0) asm volatile("s_waitcnt vmcnt(9)" ::: "memory");
                else         asm volatile("s_waitcnt vmcnt(8)" ::: "memory");
            } else if (t < 143) {
                asm volatile("s_waitcnt vmcnt(4)" ::: "memory");
            } else {
                asm volatile("s_waitcnt vmcnt(0)" ::: "memory");
            }
            __builtin_amdgcn_s_barrier();

            // ---- compute from current buffers
            const u16* Ab = &smem[AOFF(ms & 1)];
            const u16* Bb = &smem[BOFF(t & 1)];
            #pragma unroll
            for (int kk = 0; kk < 2; ++kk) {
                const int kseg = kk * 4 + lq;
                s8v af[4], bfr[4];
                #pragma unroll
                for (int i = 0; i < 4; ++i) {
                    const int ra = wm + i * 16 + lm + dx;
                    const int rb = wn + i * 16 + lm;
                    af[i]  = *(const s8v*)&Ab[ra * 64 + ((kseg ^ (ra & 7)) << 3)];
                    bfr[i] = *(const s8v*)&Bb[rb * 64 + ((kseg ^ (rb & 7)) << 3)];
                }
                #pragma unroll
                for (int mi = 0; mi < 4; ++mi)
                    #pragma unroll
                    for (int ni = 0; ni < 4; ++ni)
                        acc[mi][ni] = __builtin_amdgcn_mfma_f32_16x16x32_bf16(
                            af[mi], bfr[ni], acc[mi][ni], 0, 0, 0);
            }

            // ---- barrier2: all waves' ds_reads of this phase complete before
            // anyone issues the next overwriting global_load_lds.
            asm volatile("s_waitcnt lgkmcnt(0)" ::: "memory");
            __builtin_amdgcn_s_barrier();
        }
    }

    #pragma unroll
    for (int ni = 0; ni < 4; ++ni) {
        const int oc = oc0 + wn + ni * 16 + lm;
        const float bv = bias[oc];
        #pragma unroll
        for (int mi = 0; mi < 4; ++mi) {
            #pragma unroll
            for (int rr = 0; rr < 4; ++rr) {
                const int m = wm + mi * 16 + lq * 4 + rr;   // w index
                float v = acc[mi][ni][rr] + bv;
                v = v > 0.f ? v : 0.f;
                rpn[(gh * 128 + m) * CMID + oc] = f2bf(v);
            }
        }
    }
}

// ---------------- stage 2+3: 1x1 convs (MFMA, K-split) + softmax + proposals
// (R7 verbatim) 1024 blocks x 16 rows; 4 waves K-split; LDS reduce.
__global__ __launch_bounds__(256) void stage23(
    const u16* __restrict__ rpn, const u16* __restrict__ wc,
    const float* __restrict__ cls_b, const float* __restrict__ reg_b,
    float* __restrict__ out) {
    __shared__ float part[4][16][65];
    const int tid = threadIdx.x, lane = tid & 63, wv = tid >> 6;
    const int lm = lane & 15, lq = lane >> 4;
    const int m0 = blockIdx.x * 16;

    f4v acc[4] = {};
    const u16* arow = rpn + (m0 + lm) * CMID + wv * 128 + lq * 8;
    const u16* brow = wc + lm * CMID + wv * 128 + lq * 8;
    #pragma unroll
    for (int k = 0; k < 4; ++k) {
        s8v af = *(const s8v*)(arow + k * 32);
        #pragma unroll
        for (int ni = 0; ni < 4; ++ni) {
            s8v bf = *(const s8v*)(brow + ni * 16 * CMID + k * 32);
            acc[ni] = __builtin_amdgcn_mfma_f32_16x16x32_bf16(af, bf, acc[ni], 0, 0, 0);
        }
    }
    #pragma unroll
    for (int ni = 0; ni < 4; ++ni)
        #pragma unroll
        for (int rr = 0; rr < 4; ++rr)
            part[wv][lq * 4 + rr][ni * 16 + lm] = acc[ni][rr];
    __syncthreads();

    float vsum[4];
    const int col = tid & 63, rb = tid >> 6;
    const float bv = col < 18 ? cls_b[col] : (col < 54 ? reg_b[col - 18] : 0.f);
    #pragma unroll
    for (int rr = 0; rr < 4; ++rr) {
        const int row = rb * 4 + rr;
        vsum[rr] = part[0][row][col] + part[1][row][col]
                 + part[2][row][col] + part[3][row][col] + bv;
    }
    __syncthreads();
    #pragma unroll
    for (int rr = 0; rr < 4; ++rr)
        part[0][rb * 4 + rr][col] = vsum[rr];
    __syncthreads();

    if (tid < 144) {
        const int pl = tid / 9, a = tid - pl * 9;
        const float* v = part[0][pl];
        const int ch = 2 * a + 1;
        const int pair = (ch < 9) ? ch + 9 : ch - 9;
        const float score = 1.f / (1.f + expf(v[pair] - v[ch]));
        const float r0 = v[18 + 4 * a], r1 = v[19 + 4 * a];
        const float r2 = v[20 + 4 * a], r3 = v[21 + 4 * a];
        const float wb = WBASE[a], hb = HBASE[a];
        const int p = m0 + pl;
        const int h = p >> 7, w = p & 127;
        float* o = out + (p * 9 + a) * 5;
        o[0] = h * 16.f + wb * r0;
        o[1] = w * 16.f + hb * r1;
        o[2] = wb + expf(r2);
        o[3] = hb + expf(r3);
        o[4] = score;
    }
}

extern "C" void kernel_launch(void* const* d_in, const int* in_sizes, int n_in,
                              void* d_out, int out_size, void* d_ws, size_t ws_size,
                              hipStream_t stream) {
    const float* x      = (const float*)d_in[0];
    const float* base_w = (const float*)d_in[1];
    const float* base_b = (const float*)d_in[2];
    const float* cls_w  = (const float*)d_in[3];
    const float* cls_b  = (const float*)d_in[4];
    const float* reg_w  = (const float*)d_in[5];
    const float* reg_b  = (const float*)d_in[6];
    float* out = (float*)d_out;

    char* ws = (char*)d_ws;
    u16* xpad = (u16*)ws;                                   // 34,611,200 B
    u16* wt   = (u16*)(ws + 34611200);                      //  9,437,184 B
    u16* wc   = (u16*)(ws + 34611200 + 9437184);            //     65,536 B
    u16* rpn  = (u16*)(ws + 34611200 + 9437184 + 65536);    // 16,777,216 B

    prep_all<<<1410, 256, 0, stream>>>(x, base_w, cls_w, reg_w, xpad, wt, wc);
    gemm_conv<<<512, 256, 0, stream>>>(xpad, wt, base_b, rpn);
    stage23<<<1024, 256, 0, stream>>>(rpn, wc, cls_b, reg_b, out);
}

// Round 3
// 260.370 us; speedup vs baseline: 1.0522x; 1.0522x over previous
//
#include <hip/hip_runtime.h>
#include <hip/hip_bf16.h>

typedef unsigned short u16;
typedef short s8v __attribute__((ext_vector_type(8)));
typedef float f4v __attribute__((ext_vector_type(4)));

#define F 128
#define CIN 1024
#define CMID 512
#define XP 130
#define K9 9216

// gemm LDS element offsets (u16 units)
#define A_ELEMS 8704           // 136 rows * 64
#define B_ELEMS 8192           // 128 rows * 64
#define AOFF(b) ((b) * A_ELEMS)
#define BOFF(b) (2 * A_ELEMS + (b) * B_ELEMS)

__device__ __forceinline__ u16 f2bf(float v) {
    union { float f; unsigned u; } x; x.f = v;
    unsigned r = x.u + 0x7fff + ((x.u >> 16) & 1);
    return (u16)(r >> 16);
}
__device__ __forceinline__ float bf2f(u16 u) {
    union { unsigned u; float f; } x; x.u = ((unsigned)u) << 16; return x.f;
}

__device__ __forceinline__ void gl16(const u16* g, u16* l) {
    __builtin_amdgcn_global_load_lds(
        (const __attribute__((address_space(1))) void*)g,
        (__attribute__((address_space(3))) void*)l,
        16, 0, 0);
}

// anchor base sizes: ratios {0.5,1,2} x scales {8,16,32}
__constant__ float WBASE[9] = {184.f, 368.f, 736.f, 128.f, 256.f, 512.f,  88.f, 176.f, 352.f};
__constant__ float HBASE[9] = { 96.f, 192.f, 384.f, 128.f, 256.f, 512.f, 176.f, 352.f, 704.f};

// ---------------- fused prep ------------------------------------------------
// blocks [0,512): transpose (h, c-quarter); [512,1024): wt; [1024,1282): border;
// [1282,1410): wc
__global__ __launch_bounds__(256) void prep_all(
    const float* __restrict__ x, const float* __restrict__ bw,
    const float* __restrict__ cls_w, const float* __restrict__ reg_w,
    u16* __restrict__ xpad, u16* __restrict__ wt, u16* __restrict__ wc) {
    __shared__ char ldsraw[128 * 65 * 4];   // 33280 B (wt needs 18594)
    const int b = blockIdx.x;
    const int tid = threadIdx.x;

    if (b < 512) {                       // ---- x transpose+pad, fat blocks
        float (*lds)[65] = (float(*)[65])ldsraw;   // [w][c] per 64-c chunk
        const int h  = b >> 2;
        const int c0 = (b & 3) * 256;
        #pragma unroll 1
        for (int cc = 0; cc < 4; ++cc) {
            const int cb = c0 + cc * 64;
            {   // read: 512B-contiguous f4v per half-wave, scatter to [w][c]
                const int w4 = (tid & 31) * 4;
                const int cl = tid >> 5;         // 0..7
                #pragma unroll
                for (int p = 0; p < 8; ++p) {
                    const int c = p * 8 + cl;
                    f4v v = *(const f4v*)&x[(cb + c) * (F * F) + h * F + w4];
                    #pragma unroll
                    for (int k = 0; k < 4; ++k) lds[w4 + k][c] = v[k];
                }
            }
            __syncthreads();
            {   // write: 8 scalar LDS reads (2-way, free) -> s8v store
                const int cs = (tid & 7) * 8;
                const int wb = tid >> 3;         // 0..31
                #pragma unroll
                for (int p = 0; p < 4; ++p) {
                    const int w = p * 32 + wb;
                    s8v v;
                    #pragma unroll
                    for (int j = 0; j < 8; ++j) v[j] = (short)f2bf(lds[w][cs + j]);
                    *(s8v*)&xpad[((h + 1) * XP + (w + 1)) * CIN + cb + cs] = v;
                }
            }
            __syncthreads();
        }
    } else if (b < 1024) {               // ---- base_w OIHW -> [oc][dydx][c]
        u16* lds = (u16*)ldsraw;         // stride 1033 breaks bank conflicts
        const int oc = b - 512;
        for (int k = 0; k < 36; ++k) {
            int idx = k * 256 + tid;     // (c,dydx) linear, c-major
            float v = bw[oc * K9 + idx];
            int c = idx / 9, q = idx - c * 9;
            lds[q * 1033 + c] = f2bf(v);
        }
        __syncthreads();
        for (int k = 0; k < 36; ++k) {
            int idx = k * 256 + tid;
            int q = idx >> 10, c = idx & 1023;
            wt[oc * K9 + idx] = lds[q * 1033 + c];
        }
    } else if (b < 1282) {               // ---- border zero (vectorized)
        int t = (b - 1024) * 256 + tid;  // 516*128 chunks of 8 u16
        int cell = t >> 7, c8 = (t & 127) * 8;
        int h, w;
        if (cell < 130)      { h = 0;   w = cell; }
        else if (cell < 260) { h = 129; w = cell - 130; }
        else { int rm = cell - 260; h = 1 + (rm >> 1); w = (rm & 1) * 129; }
        s8v z = {};
        *(s8v*)&xpad[(h * XP + w) * CIN + c8] = z;
    } else {                             // ---- combined 1x1 weights
        int t = (b - 1282) * 256 + tid;  // 64*512
        int oc = t >> 9, c = t & 511;
        float v = 0.f;
        if (oc < 18)      v = cls_w[oc * 512 + c];
        else if (oc < 54) v = reg_w[(oc - 18) * 512 + c];
        wc[t] = f2bf(v);
    }
}

// ---------------- stage 1: implicit-GEMM 3x3 conv + bias + ReLU ------------
// R7 structure verbatim (139 us known-good) + T1 XCD-aware work remap:
// hardware dispatches bid round-robin (xcd = bid%8); remap so XCD k owns
// work ids [64k, 64k+64) = gh rows [16k,16k+16) x all 4 oc-quarters.
// A working set/XCD = 18 rows ~ 4.8 MB (L2-resident); all 512 blocks are
// co-resident (2/CU) so same-quarter blocks share B lines concurrently.
__global__ __launch_bounds__(256, 2) void gemm_conv(
    const u16* __restrict__ xpad, const u16* __restrict__ wt,
    const float* __restrict__ bias, u16* __restrict__ rpn) {
    __shared__ u16 smem[2 * A_ELEMS + 2 * B_ELEMS];   // 67584 B
    const int tid = threadIdx.x;
    const int w_id = (blockIdx.x & 7) * 64 + (blockIdx.x >> 3);   // XCD remap
    const int oc0 = ((w_id & 7) >> 1) * 128;
    const int gh  = (w_id >> 3) * 2 + (w_id & 1);

    const int lane = tid & 63;
    const int wv = tid >> 6;
    const int lm = lane & 15;
    const int lq = lane >> 4;
    const int wm = (wv >> 1) * 64;
    const int wn = (wv & 1) * 64;

    // source-side XOR swizzle: lane L stages data seg (L&7)^((L>>3)&7) of its row
    const int sw = (lane & 7) ^ ((lane >> 3) & 7);
    const u16* pA = xpad + (lane >> 3) * CIN + sw * 8;
    const u16* pB = wt + (size_t)(oc0 + wv * 32 + (lane >> 3)) * K9 + sw * 8;

    f4v acc[4][4] = {};

    auto issueA = [&](int ms) {
        const int dy = ms >> 4, cc = ms & 15;
        const u16* src = pA + ((gh + dy) * XP) * CIN + cc * 64;
        u16* dst = &smem[AOFF(ms & 1)];
        #pragma unroll
        for (int jj = 0; jj < 4; ++jj) {
            const int ci = wv * 4 + jj;
            gl16(src + ci * 8 * CIN, dst + ci * 512);
        }
        if (wv == 0) gl16(src + 16 * 8 * CIN, dst + 16 * 512);  // rows 128..135
    };
    auto issueB = [&](int ms, int dx, int buf) {
        const int dy = ms >> 4, cc = ms & 15;
        const int dydx = dy * 3 + dx;
        const u16* src = pB + dydx * CIN + cc * 64;
        u16* dst = &smem[BOFF(buf) + wv * 32 * 64];
        #pragma unroll
        for (int jj = 0; jj < 4; ++jj)
            gl16(src + jj * 8 * K9, dst + jj * 8 * 64);
    };

    issueA(0);
    issueB(0, 0, 0);
    __syncthreads();

    int t = 0;
    for (int ms = 0; ms < 48; ++ms) {
        const u16* Ab = &smem[AOFF(ms & 1)];
        #pragma unroll
        for (int dx = 0; dx < 3; ++dx, ++t) {
            if (t + 1 < 144) {
                const int msn = (dx == 2) ? ms + 1 : ms;
                const int dxn = (dx == 2) ? 0 : dx + 1;
                issueB(msn, dxn, (t + 1) & 1);
            }
            if (dx == 0 && ms + 1 < 48) issueA(ms + 1);
            const u16* Bb = &smem[BOFF(t & 1)];
            #pragma unroll
            for (int kk = 0; kk < 2; ++kk) {
                const int kseg = kk * 4 + lq;
                s8v af[4], bfr[4];
                #pragma unroll
                for (int i = 0; i < 4; ++i) {
                    const int ra = wm + i * 16 + lm + dx;
                    const int rb = wn + i * 16 + lm;
                    af[i]  = *(const s8v*)&Ab[ra * 64 + ((kseg ^ (ra & 7)) << 3)];
                    bfr[i] = *(const s8v*)&Bb[rb * 64 + ((kseg ^ (rb & 7)) << 3)];
                }
                #pragma unroll
                for (int mi = 0; mi < 4; ++mi)
                    #pragma unroll
                    for (int ni = 0; ni < 4; ++ni)
                        acc[mi][ni] = __builtin_amdgcn_mfma_f32_16x16x32_bf16(
                            af[mi], bfr[ni], acc[mi][ni], 0, 0, 0);
            }
            __syncthreads();
        }
    }

    #pragma unroll
    for (int ni = 0; ni < 4; ++ni) {
        const int oc = oc0 + wn + ni * 16 + lm;
        const float bv = bias[oc];
        #pragma unroll
        for (int mi = 0; mi < 4; ++mi) {
            #pragma unroll
            for (int rr = 0; rr < 4; ++rr) {
                const int m = wm + mi * 16 + lq * 4 + rr;   // w index
                float v = acc[mi][ni][rr] + bv;
                v = v > 0.f ? v : 0.f;
                rpn[(gh * 128 + m) * CMID + oc] = f2bf(v);
            }
        }
    }
}

// ---------------- stage 2+3: 1x1 convs (MFMA, K-split) + softmax + proposals
// (R7 verbatim) 1024 blocks x 16 rows; 4 waves K-split; LDS reduce.
__global__ __launch_bounds__(256) void stage23(
    const u16* __restrict__ rpn, const u16* __restrict__ wc,
    const float* __restrict__ cls_b, const float* __restrict__ reg_b,
    float* __restrict__ out) {
    __shared__ float part[4][16][65];
    const int tid = threadIdx.x, lane = tid & 63, wv = tid >> 6;
    const int lm = lane & 15, lq = lane >> 4;
    const int m0 = blockIdx.x * 16;

    f4v acc[4] = {};
    const u16* arow = rpn + (m0 + lm) * CMID + wv * 128 + lq * 8;
    const u16* brow = wc + lm * CMID + wv * 128 + lq * 8;
    #pragma unroll
    for (int k = 0; k < 4; ++k) {
        s8v af = *(const s8v*)(arow + k * 32);
        #pragma unroll
        for (int ni = 0; ni < 4; ++ni) {
            s8v bf = *(const s8v*)(brow + ni * 16 * CMID + k * 32);
            acc[ni] = __builtin_amdgcn_mfma_f32_16x16x32_bf16(af, bf, acc[ni], 0, 0, 0);
        }
    }
    #pragma unroll
    for (int ni = 0; ni < 4; ++ni)
        #pragma unroll
        for (int rr = 0; rr < 4; ++rr)
            part[wv][lq * 4 + rr][ni * 16 + lm] = acc[ni][rr];
    __syncthreads();

    float vsum[4];
    const int col = tid & 63, rb = tid >> 6;
    const float bv = col < 18 ? cls_b[col] : (col < 54 ? reg_b[col - 18] : 0.f);
    #pragma unroll
    for (int rr = 0; rr < 4; ++rr) {
        const int row = rb * 4 + rr;
        vsum[rr] = part[0][row][col] + part[1][row][col]
                 + part[2][row][col] + part[3][row][col] + bv;
    }
    __syncthreads();
    #pragma unroll
    for (int rr = 0; rr < 4; ++rr)
        part[0][rb * 4 + rr][col] = vsum[rr];
    __syncthreads();

    if (tid < 144) {
        const int pl = tid / 9, a = tid - pl * 9;
        const float* v = part[0][pl];
        const int ch = 2 * a + 1;
        const int pair = (ch < 9) ? ch + 9 : ch - 9;
        const float score = 1.f / (1.f + expf(v[pair] - v[ch]));
        const float r0 = v[18 + 4 * a], r1 = v[19 + 4 * a];
        const float r2 = v[20 + 4 * a], r3 = v[21 + 4 * a];
        const float wb = WBASE[a], hb = HBASE[a];
        const int p = m0 + pl;
        const int h = p >> 7, w = p & 127;
        float* o = out + (p * 9 + a) * 5;
        o[0] = h * 16.f + wb * r0;
        o[1] = w * 16.f + hb * r1;
        o[2] = wb + expf(r2);
        o[3] = hb + expf(r3);
        o[4] = score;
    }
}

extern "C" void kernel_launch(void* const* d_in, const int* in_sizes, int n_in,
                              void* d_out, int out_size, void* d_ws, size_t ws_size,
                              hipStream_t stream) {
    const float* x      = (const float*)d_in[0];
    const float* base_w = (const float*)d_in[1];
    const float* base_b = (const float*)d_in[2];
    const float* cls_w  = (const float*)d_in[3];
    const float* cls_b  = (const float*)d_in[4];
    const float* reg_w  = (const float*)d_in[5];
    const float* reg_b  = (const float*)d_in[6];
    float* out = (float*)d_out;

    char* ws = (char*)d_ws;
    u16* xpad = (u16*)ws;                                   // 34,611,200 B
    u16* wt   = (u16*)(ws + 34611200);                      //  9,437,184 B
    u16* wc   = (u16*)(ws + 34611200 + 9437184);            //     65,536 B
    u16* rpn  = (u16*)(ws + 34611200 + 9437184 + 65536);    // 16,777,216 B

    prep_all<<<1410, 256, 0, stream>>>(x, base_w, cls_w, reg_w, xpad, wt, wc);
    gemm_conv<<<512, 256, 0, stream>>>(xpad, wt, base_b, rpn);
    stage23<<<1024, 256, 0, stream>>>(rpn, wc, cls_b, reg_b, out);
}

// Round 4
// 259.748 us; speedup vs baseline: 1.0547x; 1.0024x over previous
//
#include <hip/hip_runtime.h>
#include <hip/hip_bf16.h>

typedef unsigned short u16;
typedef short s4v __attribute__((ext_vector_type(4)));
typedef short s8v __attribute__((ext_vector_type(8)));
typedef float f4v __attribute__((ext_vector_type(4)));

#define F 128
#define CIN 1024
#define CMID 512
#define XP 130
#define K9 9216

// gemm LDS element offsets (u16 units)
#define A_ELEMS 8704           // 136 rows * 64
#define B_ELEMS 8192           // 128 rows * 64
#define AOFF(b) ((b) * A_ELEMS)
#define BOFF(b) (2 * A_ELEMS + (b) * B_ELEMS)

__device__ __forceinline__ u16 f2bf(float v) {
    union { float f; unsigned u; } x; x.f = v;
    unsigned r = x.u + 0x7fff + ((x.u >> 16) & 1);
    return (u16)(r >> 16);
}

__device__ __forceinline__ void gl16(const u16* g, u16* l) {
    __builtin_amdgcn_global_load_lds(
        (const __attribute__((address_space(1))) void*)g,
        (__attribute__((address_space(3))) void*)l,
        16, 0, 0);
}

// anchor base sizes: ratios {0.5,1,2} x scales {8,16,32}
__constant__ float WBASE[9] = {184.f, 368.f, 736.f, 128.f, 256.f, 512.f,  88.f, 176.f, 352.f};
__constant__ float HBASE[9] = { 96.f, 192.f, 384.f, 128.f, 256.f, 512.f, 176.f, 352.f, 704.f};

// ---------------- fused prep ------------------------------------------------
// blocks [0,2048): transpose (h, 64-c chunk) — 16.9KB LDS, 8 blocks/CU;
// [2048,2560): wt direct (no LDS); [2560,2818): border; [2818,2946): wc
__global__ __launch_bounds__(256) void prep_all(
    const float* __restrict__ x, const float* __restrict__ bw,
    const float* __restrict__ cls_w, const float* __restrict__ reg_w,
    u16* __restrict__ xpad, u16* __restrict__ wt, u16* __restrict__ wc) {
    __shared__ u16 ldsT[64 * 132];     // 16896 B -> high occupancy
    const int b = blockIdx.x;
    const int tid = threadIdx.x;

    if (b < 2048) {                      // ---- x transpose+pad (thin blocks)
        const int h  = b >> 4;
        const int cb = (b & 15) * 64;
        {   // read f32, convert to bf16, packed b64 LDS write ([c][w] layout)
            const int L = tid & 31, cl = tid >> 5;    // w4 lane, c sub-lane
            const int w4 = L * 4;
            #pragma unroll
            for (int p = 0; p < 8; ++p) {
                const int c = p * 8 + cl;
                f4v v = *(const f4v*)&x[(cb + c) * (F * F) + h * F + w4];
                s4v pk;
                #pragma unroll
                for (int k = 0; k < 4; ++k) pk[k] = (short)f2bf(v[k]);
                *(s4v*)&ldsT[c * 132 + w4] = pk;      // byte addr 264c+8L: 8-aligned
            }
        }
        __syncthreads();
        {   // gather 8 consecutive c per lane -> one s8v global store
            const int cs = (tid & 7) * 8;
            const int wb = tid >> 3;                  // 0..31
            #pragma unroll
            for (int p = 0; p < 4; ++p) {
                const int w = p * 32 + wb;
                s8v o;
                #pragma unroll
                for (int j = 0; j < 8; ++j) o[j] = (short)ldsT[(cs + j) * 132 + w];
                *(s8v*)&xpad[((h + 1) * XP + (w + 1)) * CIN + cb + cs] = o;
            }
        }
    } else if (b < 2560) {               // ---- base_w OIHW -> [oc][dydx][c], direct
        const int oc = b - 2048;
        #pragma unroll 1
        for (int p = 0; p < 4; ++p) {
            const int c = p * 256 + tid;
            const float* src = bw + oc * K9 + c * 9;  // 9 consecutive f32 per c
            #pragma unroll
            for (int q = 0; q < 9; ++q)
                wt[oc * K9 + q * 1024 + c] = f2bf(src[q]);   // coalesced u16 stores
        }
    } else if (b < 2818) {               // ---- border zero (vectorized)
        int t = (b - 2560) * 256 + tid;  // 516*128 chunks of 8 u16
        int cell = t >> 7, c8 = (t & 127) * 8;
        int h, w;
        if (cell < 130)      { h = 0;   w = cell; }
        else if (cell < 260) { h = 129; w = cell - 130; }
        else { int rm = cell - 260; h = 1 + (rm >> 1); w = (rm & 1) * 129; }
        s8v z = {};
        *(s8v*)&xpad[(h * XP + w) * CIN + c8] = z;
    } else {                             // ---- combined 1x1 weights
        int t = (b - 2818) * 256 + tid;  // 64*512
        int oc = t >> 9, c = t & 511;
        float v = 0.f;
        if (oc < 18)      v = cls_w[oc * 512 + c];
        else if (oc < 54) v = reg_w[(oc - 18) * 512 + c];
        wc[t] = f2bf(v);
    }
}

// ---------------- stage 1: implicit-GEMM 3x3 conv + bias + ReLU ------------
// R7 structure verbatim (139 us known-good) + T1 XCD-aware work remap
// (round 3: FETCH 224->110 MB confirmed, time neutral — keep).
__global__ __launch_bounds__(256, 2) void gemm_conv(
    const u16* __restrict__ xpad, const u16* __restrict__ wt,
    const float* __restrict__ bias, u16* __restrict__ rpn) {
    __shared__ u16 smem[2 * A_ELEMS + 2 * B_ELEMS];   // 67584 B
    const int tid = threadIdx.x;
    const int w_id = (blockIdx.x & 7) * 64 + (blockIdx.x >> 3);   // XCD remap
    const int oc0 = ((w_id & 7) >> 1) * 128;
    const int gh  = (w_id >> 3) * 2 + (w_id & 1);

    const int lane = tid & 63;
    const int wv = tid >> 6;
    const int lm = lane & 15;
    const int lq = lane >> 4;
    const int wm = (wv >> 1) * 64;
    const int wn = (wv & 1) * 64;

    // source-side XOR swizzle: lane L stages data seg (L&7)^((L>>3)&7) of its row
    const int sw = (lane & 7) ^ ((lane >> 3) & 7);
    const u16* pA = xpad + (lane >> 3) * CIN + sw * 8;
    const u16* pB = wt + (size_t)(oc0 + wv * 32 + (lane >> 3)) * K9 + sw * 8;

    f4v acc[4][4] = {};

    auto issueA = [&](int ms) {
        const int dy = ms >> 4, cc = ms & 15;
        const u16* src = pA + ((gh + dy) * XP) * CIN + cc * 64;
        u16* dst = &smem[AOFF(ms & 1)];
        #pragma unroll
        for (int jj = 0; jj < 4; ++jj) {
            const int ci = wv * 4 + jj;
            gl16(src + ci * 8 * CIN, dst + ci * 512);
        }
        if (wv == 0) gl16(src + 16 * 8 * CIN, dst + 16 * 512);  // rows 128..135
    };
    auto issueB = [&](int ms, int dx, int buf) {
        const int dy = ms >> 4, cc = ms & 15;
        const int dydx = dy * 3 + dx;
        const u16* src = pB + dydx * CIN + cc * 64;
        u16* dst = &smem[BOFF(buf) + wv * 32 * 64];
        #pragma unroll
        for (int jj = 0; jj < 4; ++jj)
            gl16(src + jj * 8 * K9, dst + jj * 8 * 64);
    };

    issueA(0);
    issueB(0, 0, 0);
    __syncthreads();

    int t = 0;
    for (int ms = 0; ms < 48; ++ms) {
        const u16* Ab = &smem[AOFF(ms & 1)];
        #pragma unroll
        for (int dx = 0; dx < 3; ++dx, ++t) {
            if (t + 1 < 144) {
                const int msn = (dx == 2) ? ms + 1 : ms;
                const int dxn = (dx == 2) ? 0 : dx + 1;
                issueB(msn, dxn, (t + 1) & 1);
            }
            if (dx == 0 && ms + 1 < 48) issueA(ms + 1);
            const u16* Bb = &smem[BOFF(t & 1)];
            #pragma unroll
            for (int kk = 0; kk < 2; ++kk) {
                const int kseg = kk * 4 + lq;
                s8v af[4], bfr[4];
                #pragma unroll
                for (int i = 0; i < 4; ++i) {
                    const int ra = wm + i * 16 + lm + dx;
                    const int rb = wn + i * 16 + lm;
                    af[i]  = *(const s8v*)&Ab[ra * 64 + ((kseg ^ (ra & 7)) << 3)];
                    bfr[i] = *(const s8v*)&Bb[rb * 64 + ((kseg ^ (rb & 7)) << 3)];
                }
                #pragma unroll
                for (int mi = 0; mi < 4; ++mi)
                    #pragma unroll
                    for (int ni = 0; ni < 4; ++ni)
                        acc[mi][ni] = __builtin_amdgcn_mfma_f32_16x16x32_bf16(
                            af[mi], bfr[ni], acc[mi][ni], 0, 0, 0);
            }
            __syncthreads();
        }
    }

    #pragma unroll
    for (int ni = 0; ni < 4; ++ni) {
        const int oc = oc0 + wn + ni * 16 + lm;
        const float bv = bias[oc];
        #pragma unroll
        for (int mi = 0; mi < 4; ++mi) {
            #pragma unroll
            for (int rr = 0; rr < 4; ++rr) {
                const int m = wm + mi * 16 + lq * 4 + rr;   // w index
                float v = acc[mi][ni][rr] + bv;
                v = v > 0.f ? v : 0.f;
                rpn[(gh * 128 + m) * CMID + oc] = f2bf(v);
            }
        }
    }
}

// ---------------- stage 2+3: 1x1 convs (MFMA, K-split) + softmax + proposals
// v4: 512 blocks x 32 rows (2 groups of 16) — halves block count / sync
// latency overhead; same wave structure per group.
__global__ __launch_bounds__(256) void stage23(
    const u16* __restrict__ rpn, const u16* __restrict__ wc,
    const float* __restrict__ cls_b, const float* __restrict__ reg_b,
    float* __restrict__ out) {
    __shared__ float part[4][32][65];
    const int tid = threadIdx.x, lane = tid & 63, wv = tid >> 6;
    const int lm = lane & 15, lq = lane >> 4;
    const int m0 = blockIdx.x * 32;

    #pragma unroll
    for (int g = 0; g < 2; ++g) {
        f4v acc[4] = {};
        const u16* arow = rpn + (m0 + g * 16 + lm) * CMID + wv * 128 + lq * 8;
        const u16* brow = wc + lm * CMID + wv * 128 + lq * 8;
        #pragma unroll
        for (int k = 0; k < 4; ++k) {
            s8v af = *(const s8v*)(arow + k * 32);
            #pragma unroll
            for (int ni = 0; ni < 4; ++ni) {
                s8v bf = *(const s8v*)(brow + ni * 16 * CMID + k * 32);
                acc[ni] = __builtin_amdgcn_mfma_f32_16x16x32_bf16(af, bf, acc[ni], 0, 0, 0);
            }
        }
        #pragma unroll
        for (int ni = 0; ni < 4; ++ni)
            #pragma unroll
            for (int rr = 0; rr < 4; ++rr)
                part[wv][g * 16 + lq * 4 + rr][ni * 16 + lm] = acc[ni][rr];
    }
    __syncthreads();

    float vsum[8];
    const int col = tid & 63, rb = tid >> 6;
    const float bv = col < 18 ? cls_b[col] : (col < 54 ? reg_b[col - 18] : 0.f);
    #pragma unroll
    for (int rr = 0; rr < 8; ++rr) {
        const int row = rb * 8 + rr;
        vsum[rr] = part[0][row][col] + part[1][row][col]
                 + part[2][row][col] + part[3][row][col] + bv;
    }
    __syncthreads();
    #pragma unroll
    for (int rr = 0; rr < 8; ++rr)
        part[0][rb * 8 + rr][col] = vsum[rr];
    __syncthreads();

    #pragma unroll 1
    for (int g = 0; g < 2; ++g) {
        if (tid < 144) {
            const int pl0 = tid / 9, a = tid - pl0 * 9;
            const int pl = g * 16 + pl0;
            const float* v = part[0][pl];
            const int ch = 2 * a + 1;
            const int pair = (ch < 9) ? ch + 9 : ch - 9;
            const float score = 1.f / (1.f + expf(v[pair] - v[ch]));
            const float r0 = v[18 + 4 * a], r1 = v[19 + 4 * a];
            const float r2 = v[20 + 4 * a], r3 = v[21 + 4 * a];
            const float wb = WBASE[a], hb = HBASE[a];
            const int p = m0 + pl;
            const int h = p >> 7, w = p & 127;
            float* o = out + (p * 9 + a) * 5;
            o[0] = h * 16.f + wb * r0;
            o[1] = w * 16.f + hb * r1;
            o[2] = wb + expf(r2);
            o[3] = hb + expf(r3);
            o[4] = score;
        }
    }
}

extern "C" void kernel_launch(void* const* d_in, const int* in_sizes, int n_in,
                              void* d_out, int out_size, void* d_ws, size_t ws_size,
                              hipStream_t stream) {
    const float* x      = (const float*)d_in[0];
    const float* base_w = (const float*)d_in[1];
    const float* base_b = (const float*)d_in[2];
    const float* cls_w  = (const float*)d_in[3];
    const float* cls_b  = (const float*)d_in[4];
    const float* reg_w  = (const float*)d_in[5];
    const float* reg_b  = (const float*)d_in[6];
    float* out = (float*)d_out;

    char* ws = (char*)d_ws;
    u16* xpad = (u16*)ws;                                   // 34,611,200 B
    u16* wt   = (u16*)(ws + 34611200);                      //  9,437,184 B
    u16* wc   = (u16*)(ws + 34611200 + 9437184);            //     65,536 B
    u16* rpn  = (u16*)(ws + 34611200 + 9437184 + 65536);    // 16,777,216 B

    prep_all<<<2946, 256, 0, stream>>>(x, base_w, cls_w, reg_w, xpad, wt, wc);
    gemm_conv<<<512, 256, 0, stream>>>(xpad, wt, base_b, rpn);
    stage23<<<512, 256, 0, stream>>>(rpn, wc, cls_b, reg_b, out);
}

// Round 5
// 259.067 us; speedup vs baseline: 1.0575x; 1.0026x over previous
//
#include <hip/hip_runtime.h>
#include <hip/hip_bf16.h>

typedef unsigned short u16;
typedef short s4v __attribute__((ext_vector_type(4)));
typedef short s8v __attribute__((ext_vector_type(8)));
typedef float f4v __attribute__((ext_vector_type(4)));

#define F 128
#define CIN 1024
#define CMID 512
#define XP 130
#define K9 9216

// gemm LDS element offsets (u16 units): 2 A bufs + 3 B bufs = 133120 B
#define A_ELEMS 8704           // 136 rows * 64
#define B_ELEMS 16384          // 256 rows * 64
#define AOFF(b) ((b) * A_ELEMS)
#define BOFF(b) (2 * A_ELEMS + (b) * B_ELEMS)

__device__ __forceinline__ u16 f2bf(float v) {
    union { float f; unsigned u; } x; x.f = v;
    unsigned r = x.u + 0x7fff + ((x.u >> 16) & 1);
    return (u16)(r >> 16);
}

__device__ __forceinline__ void gl16(const u16* g, u16* l) {
    __builtin_amdgcn_global_load_lds(
        (const __attribute__((address_space(1))) void*)g,
        (__attribute__((address_space(3))) void*)l,
        16, 0, 0);
}

// anchor base sizes: ratios {0.5,1,2} x scales {8,16,32}
__constant__ float WBASE[9] = {184.f, 368.f, 736.f, 128.f, 256.f, 512.f,  88.f, 176.f, 352.f};
__constant__ float HBASE[9] = { 96.f, 192.f, 384.f, 128.f, 256.f, 512.f, 176.f, 352.f, 704.f};

// ---------------- fused prep (round-4 version, at floor) --------------------
__global__ __launch_bounds__(256) void prep_all(
    const float* __restrict__ x, const float* __restrict__ bw,
    const float* __restrict__ cls_w, const float* __restrict__ reg_w,
    u16* __restrict__ xpad, u16* __restrict__ wt, u16* __restrict__ wc) {
    __shared__ u16 ldsT[64 * 132];     // 16896 B -> high occupancy
    const int b = blockIdx.x;
    const int tid = threadIdx.x;

    if (b < 2048) {                      // ---- x transpose+pad (thin blocks)
        const int h  = b >> 4;
        const int cb = (b & 15) * 64;
        {   // read f32, convert to bf16, packed b64 LDS write ([c][w] layout)
            const int L = tid & 31, cl = tid >> 5;    // w4 lane, c sub-lane
            const int w4 = L * 4;
            #pragma unroll
            for (int p = 0; p < 8; ++p) {
                const int c = p * 8 + cl;
                f4v v = *(const f4v*)&x[(cb + c) * (F * F) + h * F + w4];
                s4v pk;
                #pragma unroll
                for (int k = 0; k < 4; ++k) pk[k] = (short)f2bf(v[k]);
                *(s4v*)&ldsT[c * 132 + w4] = pk;      // byte addr 264c+8L: 8-aligned
            }
        }
        __syncthreads();
        {   // gather 8 consecutive c per lane -> one s8v global store
            const int cs = (tid & 7) * 8;
            const int wb = tid >> 3;                  // 0..31
            #pragma unroll
            for (int p = 0; p < 4; ++p) {
                const int w = p * 32 + wb;
                s8v o;
                #pragma unroll
                for (int j = 0; j < 8; ++j) o[j] = (short)ldsT[(cs + j) * 132 + w];
                *(s8v*)&xpad[((h + 1) * XP + (w + 1)) * CIN + cb + cs] = o;
            }
        }
    } else if (b < 2560) {               // ---- base_w OIHW -> [oc][dydx][c], direct
        const int oc = b - 2048;
        #pragma unroll 1
        for (int p = 0; p < 4; ++p) {
            const int c = p * 256 + tid;
            const float* src = bw + oc * K9 + c * 9;  // 9 consecutive f32 per c
            #pragma unroll
            for (int q = 0; q < 9; ++q)
                wt[oc * K9 + q * 1024 + c] = f2bf(src[q]);   // coalesced u16 stores
        }
    } else if (b < 2818) {               // ---- border zero (vectorized)
        int t = (b - 2560) * 256 + tid;  // 516*128 chunks of 8 u16
        int cell = t >> 7, c8 = (t & 127) * 8;
        int h, w;
        if (cell < 130)      { h = 0;   w = cell; }
        else if (cell < 260) { h = 129; w = cell - 130; }
        else { int rm = cell - 260; h = 1 + (rm >> 1); w = (rm & 1) * 129; }
        s8v z = {};
        *(s8v*)&xpad[(h * XP + w) * CIN + c8] = z;
    } else {                             // ---- combined 1x1 weights
        int t = (b - 2818) * 256 + tid;  // 64*512
        int oc = t >> 9, c = t & 511;
        float v = 0.f;
        if (oc < 18)      v = cls_w[oc * 512 + c];
        else if (oc < 54) v = reg_w[(oc - 18) * 512 + c];
        wc[t] = f2bf(v);
    }
}

// ---------------- stage 1: implicit-GEMM 3x3 conv + bias + ReLU ------------
// v3: deep-pipelined 512-thread blocks. 128(M) x 256(N), 8 waves of 64x64
// (proven fragment math), 1 block/CU x 2 waves/SIMD, B triple-buffered /
// A double-buffered (133 KB LDS). Per phase: counted vmcnt -> s_barrier ->
// ds_reads -> stage t+2 -> MFMA. Issue->consume distance 2 phases; no drains.
// vmcnt accounting (stage order: B then A, after barrier):
//   dx0: newer-than-B(t) = B(t+1) only -> vmcnt(4)
//   dx1/dx2 (ms<47): B(4) + A(2; wave0 3) -> vmcnt(6)/(7)
//   t=142 -> 4; t=143 -> 0 (staging stopped)
__global__ __launch_bounds__(512, 1) void gemm_conv(
    const u16* __restrict__ xpad, const u16* __restrict__ wt,
    const float* __restrict__ bias, u16* __restrict__ rpn) {
    __shared__ u16 smem[2 * A_ELEMS + 3 * B_ELEMS];   // 133120 B
    const int tid = threadIdx.x;
    const int w_id = (blockIdx.x & 7) * 32 + (blockIdx.x >> 3);   // XCD remap
    const int oc0 = (w_id & 1) * 256;
    const int gh  = w_id >> 1;

    const int lane = tid & 63;
    const int wv = tid >> 6;          // 0..7
    const int lm = lane & 15;
    const int lq = lane >> 4;
    const int wm = (wv >> 2) * 64;    // 2 M-groups
    const int wn = (wv & 3) * 64;     // 4 N-groups

    // source-side XOR swizzle: lane L stages data seg (L&7)^((L>>3)&7) of its row
    const int sw = (lane & 7) ^ ((lane >> 3) & 7);
    const u16* pA = xpad + (lane >> 3) * CIN + sw * 8;
    const u16* pB = wt + (size_t)(oc0 + wv * 32 + (lane >> 3)) * K9 + sw * 8;

    f4v acc[4][4] = {};

    auto issueA = [&](int ms) {
        const int dy = ms >> 4, cc = ms & 15;
        const u16* src = pA + ((gh + dy) * XP) * CIN + cc * 64;
        u16* dst = &smem[AOFF(ms & 1)];
        #pragma unroll
        for (int jj = 0; jj < 2; ++jj) {
            const int ci = wv * 2 + jj;
            gl16(src + ci * 8 * CIN, dst + ci * 512);
        }
        if (wv == 0) gl16(src + 16 * 8 * CIN, dst + 16 * 512);  // rows 128..135
    };
    auto issueB = [&](int t2) {       // stage B for phase t2 into buf t2%3
        const int ms = t2 / 3, dx = t2 % 3;
        const int dy = ms >> 4, cc = ms & 15;
        const int dydx = dy * 3 + dx;
        const u16* src = pB + dydx * CIN + cc * 64;
        u16* dst = &smem[BOFF(t2 % 3) + wv * 32 * 64];
        #pragma unroll
        for (int jj = 0; jj < 4; ++jj)
            gl16(src + jj * 8 * K9, dst + jj * 8 * 64);
    };

    // prologue: A(0) first (oldest), then B(0), B(1) — vmcnt math relies on order
    issueA(0);
    issueB(0);
    issueB(1);

    for (int ms = 0; ms < 48; ++ms) {
        const u16* Ab = &smem[AOFF(ms & 1)];
        #pragma unroll
        for (int dx = 0; dx < 3; ++dx) {
            const int t = ms * 3 + dx;

            // ---- counted wait: my slice of B(t) (staged t-2) + A landed
            if (dx == 0) {
                asm volatile("s_waitcnt vmcnt(4)" ::: "memory");
            } else if (ms < 47) {
                if (wv == 0) asm volatile("s_waitcnt vmcnt(7)" ::: "memory");
                else         asm volatile("s_waitcnt vmcnt(6)" ::: "memory");
            } else if (dx == 1) {
                asm volatile("s_waitcnt vmcnt(4)" ::: "memory");
            } else {
                asm volatile("s_waitcnt vmcnt(0)" ::: "memory");
            }
            // all waves passed their own check -> whole buffer landed;
            // also: phase t-1 ds_reads completed (they fed t-1's MFMAs)
            __builtin_amdgcn_s_barrier();

            // ---- stage ahead (WAR-safe: target buf last read at t-1)
            if (t + 2 < 144) issueB(t + 2);
            if (dx == 0 && ms + 1 < 48) issueA(ms + 1);

            // ---- compute phase t from buf dx
            const u16* Bb = &smem[BOFF(dx)];
            __builtin_amdgcn_s_setprio(1);
            #pragma unroll
            for (int kk = 0; kk < 2; ++kk) {
                const int kseg = kk * 4 + lq;
                s8v af[4], bfr[4];
                #pragma unroll
                for (int i = 0; i < 4; ++i) {
                    const int ra = wm + i * 16 + lm + dx;
                    const int rb = wn + i * 16 + lm;
                    af[i]  = *(const s8v*)&Ab[ra * 64 + ((kseg ^ (ra & 7)) << 3)];
                    bfr[i] = *(const s8v*)&Bb[rb * 64 + ((kseg ^ (rb & 7)) << 3)];
                }
                #pragma unroll
                for (int mi = 0; mi < 4; ++mi)
                    #pragma unroll
                    for (int ni = 0; ni < 4; ++ni)
                        acc[mi][ni] = __builtin_amdgcn_mfma_f32_16x16x32_bf16(
                            af[mi], bfr[ni], acc[mi][ni], 0, 0, 0);
            }
            __builtin_amdgcn_s_setprio(0);
        }
    }

    #pragma unroll
    for (int ni = 0; ni < 4; ++ni) {
        const int oc = oc0 + wn + ni * 16 + lm;
        const float bv = bias[oc];
        #pragma unroll
        for (int mi = 0; mi < 4; ++mi) {
            #pragma unroll
            for (int rr = 0; rr < 4; ++rr) {
                const int m = wm + mi * 16 + lq * 4 + rr;   // w index
                float v = acc[mi][ni][rr] + bv;
                v = v > 0.f ? v : 0.f;
                rpn[(gh * 128 + m) * CMID + oc] = f2bf(v);
            }
        }
    }
}

// ---------------- stage 2+3: 1x1 convs (MFMA, K-split) + softmax + proposals
// (round-4 version) 512 blocks x 32 rows; 4 waves K-split; LDS reduce.
__global__ __launch_bounds__(256) void stage23(
    const u16* __restrict__ rpn, const u16* __restrict__ wc,
    const float* __restrict__ cls_b, const float* __restrict__ reg_b,
    float* __restrict__ out) {
    __shared__ float part[4][32][65];
    const int tid = threadIdx.x, lane = tid & 63, wv = tid >> 6;
    const int lm = lane & 15, lq = lane >> 4;
    const int m0 = blockIdx.x * 32;

    #pragma unroll
    for (int g = 0; g < 2; ++g) {
        f4v acc[4] = {};
        const u16* arow = rpn + (m0 + g * 16 + lm) * CMID + wv * 128 + lq * 8;
        const u16* brow = wc + lm * CMID + wv * 128 + lq * 8;
        #pragma unroll
        for (int k = 0; k < 4; ++k) {
            s8v af = *(const s8v*)(arow + k * 32);
            #pragma unroll
            for (int ni = 0; ni < 4; ++ni) {
                s8v bf = *(const s8v*)(brow + ni * 16 * CMID + k * 32);
                acc[ni] = __builtin_amdgcn_mfma_f32_16x16x32_bf16(af, bf, acc[ni], 0, 0, 0);
            }
        }
        #pragma unroll
        for (int ni = 0; ni < 4; ++ni)
            #pragma unroll
            for (int rr = 0; rr < 4; ++rr)
                part[wv][g * 16 + lq * 4 + rr][ni * 16 + lm] = acc[ni][rr];
    }
    __syncthreads();

    float vsum[8];
    const int col = tid & 63, rb = tid >> 6;
    const float bv = col < 18 ? cls_b[col] : (col < 54 ? reg_b[col - 18] : 0.f);
    #pragma unroll
    for (int rr = 0; rr < 8; ++rr) {
        const int row = rb * 8 + rr;
        vsum[rr] = part[0][row][col] + part[1][row][col]
                 + part[2][row][col] + part[3][row][col] + bv;
    }
    __syncthreads();
    #pragma unroll
    for (int rr = 0; rr < 8; ++rr)
        part[0][rb * 8 + rr][col] = vsum[rr];
    __syncthreads();

    #pragma unroll 1
    for (int g = 0; g < 2; ++g) {
        if (tid < 144) {
            const int pl0 = tid / 9, a = tid - pl0 * 9;
            const int pl = g * 16 + pl0;
            const float* v = part[0][pl];
            const int ch = 2 * a + 1;
            const int pair = (ch < 9) ? ch + 9 : ch - 9;
            const float score = 1.f / (1.f + expf(v[pair] - v[ch]));
            const float r0 = v[18 + 4 * a], r1 = v[19 + 4 * a];
            const float r2 = v[20 + 4 * a], r3 = v[21 + 4 * a];
            const float wb = WBASE[a], hb = HBASE[a];
            const int p = m0 + pl;
            const int h = p >> 7, w = p & 127;
            float* o = out + (p * 9 + a) * 5;
            o[0] = h * 16.f + wb * r0;
            o[1] = w * 16.f + hb * r1;
            o[2] = wb + expf(r2);
            o[3] = hb + expf(r3);
            o[4] = score;
        }
    }
}

extern "C" void kernel_launch(void* const* d_in, const int* in_sizes, int n_in,
                              void* d_out, int out_size, void* d_ws, size_t ws_size,
                              hipStream_t stream) {
    const float* x      = (const float*)d_in[0];
    const float* base_w = (const float*)d_in[1];
    const float* base_b = (const float*)d_in[2];
    const float* cls_w  = (const float*)d_in[3];
    const float* cls_b  = (const float*)d_in[4];
    const float* reg_w  = (const float*)d_in[5];
    const float* reg_b  = (const float*)d_in[6];
    float* out = (float*)d_out;

    char* ws = (char*)d_ws;
    u16* xpad = (u16*)ws;                                   // 34,611,200 B
    u16* wt   = (u16*)(ws + 34611200);                      //  9,437,184 B
    u16* wc   = (u16*)(ws + 34611200 + 9437184);            //     65,536 B
    u16* rpn  = (u16*)(ws + 34611200 + 9437184 + 65536);    // 16,777,216 B

    prep_all<<<2946, 256, 0, stream>>>(x, base_w, cls_w, reg_w, xpad, wt, wc);
    gemm_conv<<<256, 512, 0, stream>>>(xpad, wt, base_b, rpn);
    stage23<<<512, 256, 0, stream>>>(rpn, wc, cls_b, reg_b, out);
}

// Round 6
// 254.885 us; speedup vs baseline: 1.0749x; 1.0164x over previous
//
#include <hip/hip_runtime.h>
#include <hip/hip_bf16.h>

typedef unsigned short u16;
typedef short s4v __attribute__((ext_vector_type(4)));
typedef short s8v __attribute__((ext_vector_type(8)));
typedef float f4v __attribute__((ext_vector_type(4)));

#define F 128
#define CIN 1024
#define CMID 512
#define XP 130
#define K9 9216

// gemm LDS element offsets (u16 units)
#define A_ELEMS 8704           // 136 rows * 64
#define B_ELEMS 8192           // 128 rows * 64
#define AOFF(b) ((b) * A_ELEMS)
#define BOFF(b) (2 * A_ELEMS + (b) * B_ELEMS)

__device__ __forceinline__ u16 f2bf(float v) {
    union { float f; unsigned u; } x; x.f = v;
    unsigned r = x.u + 0x7fff + ((x.u >> 16) & 1);
    return (u16)(r >> 16);
}

__device__ __forceinline__ void gl16(const u16* g, u16* l) {
    __builtin_amdgcn_global_load_lds(
        (const __attribute__((address_space(1))) void*)g,
        (__attribute__((address_space(3))) void*)l,
        16, 0, 0);
}

// anchor base sizes: ratios {0.5,1,2} x scales {8,16,32}
__constant__ float WBASE[9] = {184.f, 368.f, 736.f, 128.f, 256.f, 512.f,  88.f, 176.f, 352.f};
__constant__ float HBASE[9] = { 96.f, 192.f, 384.f, 128.f, 256.f, 512.f, 176.f, 352.f, 704.f};

// ---------------- fused prep (round-4 version, at floor) --------------------
__global__ __launch_bounds__(256) void prep_all(
    const float* __restrict__ x, const float* __restrict__ bw,
    const float* __restrict__ cls_w, const float* __restrict__ reg_w,
    u16* __restrict__ xpad, u16* __restrict__ wt, u16* __restrict__ wc) {
    __shared__ u16 ldsT[64 * 132];     // 16896 B -> high occupancy
    const int b = blockIdx.x;
    const int tid = threadIdx.x;

    if (b < 2048) {                      // ---- x transpose+pad (thin blocks)
        const int h  = b >> 4;
        const int cb = (b & 15) * 64;
        {   // read f32, convert to bf16, packed b64 LDS write ([c][w] layout)
            const int L = tid & 31, cl = tid >> 5;    // w4 lane, c sub-lane
            const int w4 = L * 4;
            #pragma unroll
            for (int p = 0; p < 8; ++p) {
                const int c = p * 8 + cl;
                f4v v = *(const f4v*)&x[(cb + c) * (F * F) + h * F + w4];
                s4v pk;
                #pragma unroll
                for (int k = 0; k < 4; ++k) pk[k] = (short)f2bf(v[k]);
                *(s4v*)&ldsT[c * 132 + w4] = pk;      // byte addr 264c+8L: 8-aligned
            }
        }
        __syncthreads();
        {   // gather 8 consecutive c per lane -> one s8v global store
            const int cs = (tid & 7) * 8;
            const int wb = tid >> 3;                  // 0..31
            #pragma unroll
            for (int p = 0; p < 4; ++p) {
                const int w = p * 32 + wb;
                s8v o;
                #pragma unroll
                for (int j = 0; j < 8; ++j) o[j] = (short)ldsT[(cs + j) * 132 + w];
                *(s8v*)&xpad[((h + 1) * XP + (w + 1)) * CIN + cb + cs] = o;
            }
        }
    } else if (b < 2560) {               // ---- base_w OIHW -> [oc][dydx][c], direct
        const int oc = b - 2048;
        #pragma unroll 1
        for (int p = 0; p < 4; ++p) {
            const int c = p * 256 + tid;
            const float* src = bw + oc * K9 + c * 9;  // 9 consecutive f32 per c
            #pragma unroll
            for (int q = 0; q < 9; ++q)
                wt[oc * K9 + q * 1024 + c] = f2bf(src[q]);   // coalesced u16 stores
        }
    } else if (b < 2818) {               // ---- border zero (vectorized)
        int t = (b - 2560) * 256 + tid;  // 516*128 chunks of 8 u16
        int cell = t >> 7, c8 = (t & 127) * 8;
        int h, w;
        if (cell < 130)      { h = 0;   w = cell; }
        else if (cell < 260) { h = 129; w = cell - 130; }
        else { int rm = cell - 260; h = 1 + (rm >> 1); w = (rm & 1) * 129; }
        s8v z = {};
        *(s8v*)&xpad[(h * XP + w) * CIN + c8] = z;
    } else {                             // ---- combined 1x1 weights
        int t = (b - 2818) * 256 + tid;  // 64*512
        int oc = t >> 9, c = t & 511;
        float v = 0.f;
        if (oc < 18)      v = cls_w[oc * 512 + c];
        else if (oc < 54) v = reg_w[(oc - 18) * 512 + c];
        wc[t] = f2bf(v);
    }
}

// ---------------- stage 1: implicit-GEMM 3x3 conv + bias + ReLU ------------
// R7 geometry (64x64 waves, 256 thr, 2 blocks/CU) + T1 XCD remap, with the
// phase wait moved to the TOP of each phase: vmcnt(counted) + raw s_barrier,
// staging issued AFTER the barrier. Every wait now targets loads issued >=1
// full phase earlier (~2300 cyc slack vs ~900 cyc HBM); dx1 relaxes to
// vmcnt(4/5). Barrier count unchanged (144); no second barrier; dx unrolled.
// WAR safety: buf (t+1)&1 last ds_read in phase t-1; those reads retire
// before each wave's MFMAs, hence before it reaches this barrier.
__global__ __launch_bounds__(256, 2) void gemm_conv(
    const u16* __restrict__ xpad, const u16* __restrict__ wt,
    const float* __restrict__ bias, u16* __restrict__ rpn) {
    __shared__ u16 smem[2 * A_ELEMS + 2 * B_ELEMS];   // 67584 B
    const int tid = threadIdx.x;
    const int w_id = (blockIdx.x & 7) * 64 + (blockIdx.x >> 3);   // XCD remap
    const int oc0 = ((w_id & 7) >> 1) * 128;
    const int gh  = (w_id >> 3) * 2 + (w_id & 1);

    const int lane = tid & 63;
    const int wv = tid >> 6;
    const int lm = lane & 15;
    const int lq = lane >> 4;
    const int wm = (wv >> 1) * 64;
    const int wn = (wv & 1) * 64;

    // source-side XOR swizzle: lane L stages data seg (L&7)^((L>>3)&7) of its row
    const int sw = (lane & 7) ^ ((lane >> 3) & 7);
    const u16* pA = xpad + (lane >> 3) * CIN + sw * 8;
    const u16* pB = wt + (size_t)(oc0 + wv * 32 + (lane >> 3)) * K9 + sw * 8;

    f4v acc[4][4] = {};

    auto issueA = [&](int ms) {
        const int dy = ms >> 4, cc = ms & 15;
        const u16* src = pA + ((gh + dy) * XP) * CIN + cc * 64;
        u16* dst = &smem[AOFF(ms & 1)];
        #pragma unroll
        for (int jj = 0; jj < 4; ++jj) {
            const int ci = wv * 4 + jj;
            gl16(src + ci * 8 * CIN, dst + ci * 512);
        }
        if (wv == 0) gl16(src + 16 * 8 * CIN, dst + 16 * 512);  // rows 128..135
    };
    auto issueB = [&](int ms, int dx, int buf) {
        const int dy = ms >> 4, cc = ms & 15;
        const int dydx = dy * 3 + dx;
        const u16* src = pB + dydx * CIN + cc * 64;
        u16* dst = &smem[BOFF(buf) + wv * 32 * 64];
        #pragma unroll
        for (int jj = 0; jj < 4; ++jj)
            gl16(src + jj * 8 * K9, dst + jj * 8 * 64);
    };

    issueA(0);
    issueB(0, 0, 0);

    for (int ms = 0; ms < 48; ++ms) {
        const u16* Ab = &smem[AOFF(ms & 1)];
        #pragma unroll
        for (int dx = 0; dx < 3; ++dx) {
            const int t = ms * 3 + dx;

            // ---- top-of-phase wait: phase-t staging landed.
            // dx1: only loads newer than B(t) are this ms's A(ms+1) issues.
            if (dx == 1) {
                if (ms < 47) {
                    if (wv == 0) asm volatile("s_waitcnt vmcnt(5)" ::: "memory");
                    else         asm volatile("s_waitcnt vmcnt(4)" ::: "memory");
                } else {
                    asm volatile("s_waitcnt vmcnt(0)" ::: "memory");
                }
            } else {
                // B(t) is the newest outstanding load (issued last phase):
                // vmcnt(0), but with >=1 phase (~2300 cyc) of slack.
                asm volatile("s_waitcnt vmcnt(0)" ::: "memory");
            }
            __builtin_amdgcn_s_barrier();

            // ---- issue staging for phase t+1 (WAR-safe, see header comment)
            if (t + 1 < 144) {
                const int msn = (dx == 2) ? ms + 1 : ms;
                const int dxn = (dx == 2) ? 0 : dx + 1;
                issueB(msn, dxn, (t + 1) & 1);
            }
            if (dx == 0 && ms + 1 < 48) issueA(ms + 1);

            // ---- compute phase t
            const u16* Bb = &smem[BOFF(t & 1)];
            #pragma unroll
            for (int kk = 0; kk < 2; ++kk) {
                const int kseg = kk * 4 + lq;
                s8v af[4], bfr[4];
                #pragma unroll
                for (int i = 0; i < 4; ++i) {
                    const int ra = wm + i * 16 + lm + dx;
                    const int rb = wn + i * 16 + lm;
                    af[i]  = *(const s8v*)&Ab[ra * 64 + ((kseg ^ (ra & 7)) << 3)];
                    bfr[i] = *(const s8v*)&Bb[rb * 64 + ((kseg ^ (rb & 7)) << 3)];
                }
                #pragma unroll
                for (int mi = 0; mi < 4; ++mi)
                    #pragma unroll
                    for (int ni = 0; ni < 4; ++ni)
                        acc[mi][ni] = __builtin_amdgcn_mfma_f32_16x16x32_bf16(
                            af[mi], bfr[ni], acc[mi][ni], 0, 0, 0);
            }
            // no bottom-of-phase barrier
        }
    }

    #pragma unroll
    for (int ni = 0; ni < 4; ++ni) {
        const int oc = oc0 + wn + ni * 16 + lm;
        const float bv = bias[oc];
        #pragma unroll
        for (int mi = 0; mi < 4; ++mi) {
            #pragma unroll
            for (int rr = 0; rr < 4; ++rr) {
                const int m = wm + mi * 16 + lq * 4 + rr;   // w index
                float v = acc[mi][ni][rr] + bv;
                v = v > 0.f ? v : 0.f;
                rpn[(gh * 128 + m) * CMID + oc] = f2bf(v);
            }
        }
    }
}

// ---------------- stage 2+3: 1x1 convs (MFMA, K-split) + softmax + proposals
// (round-4 version) 512 blocks x 32 rows; 4 waves K-split; LDS reduce.
__global__ __launch_bounds__(256) void stage23(
    const u16* __restrict__ rpn, const u16* __restrict__ wc,
    const float* __restrict__ cls_b, const float* __restrict__ reg_b,
    float* __restrict__ out) {
    __shared__ float part[4][32][65];
    const int tid = threadIdx.x, lane = tid & 63, wv = tid >> 6;
    const int lm = lane & 15, lq = lane >> 4;
    const int m0 = blockIdx.x * 32;

    #pragma unroll
    for (int g = 0; g < 2; ++g) {
        f4v acc[4] = {};
        const u16* arow = rpn + (m0 + g * 16 + lm) * CMID + wv * 128 + lq * 8;
        const u16* brow = wc + lm * CMID + wv * 128 + lq * 8;
        #pragma unroll
        for (int k = 0; k < 4; ++k) {
            s8v af = *(const s8v*)(arow + k * 32);
            #pragma unroll
            for (int ni = 0; ni < 4; ++ni) {
                s8v bf = *(const s8v*)(brow + ni * 16 * CMID + k * 32);
                acc[ni] = __builtin_amdgcn_mfma_f32_16x16x32_bf16(af, bf, acc[ni], 0, 0, 0);
            }
        }
        #pragma unroll
        for (int ni = 0; ni < 4; ++ni)
            #pragma unroll
            for (int rr = 0; rr < 4; ++rr)
                part[wv][g * 16 + lq * 4 + rr][ni * 16 + lm] = acc[ni][rr];
    }
    __syncthreads();

    float vsum[8];
    const int col = tid & 63, rb = tid >> 6;
    const float bv = col < 18 ? cls_b[col] : (col < 54 ? reg_b[col - 18] : 0.f);
    #pragma unroll
    for (int rr = 0; rr < 8; ++rr) {
        const int row = rb * 8 + rr;
        vsum[rr] = part[0][row][col] + part[1][row][col]
                 + part[2][row][col] + part[3][row][col] + bv;
    }
    __syncthreads();
    #pragma unroll
    for (int rr = 0; rr < 8; ++rr)
        part[0][rb * 8 + rr][col] = vsum[rr];
    __syncthreads();

    #pragma unroll 1
    for (int g = 0; g < 2; ++g) {
        if (tid < 144) {
            const int pl0 = tid / 9, a = tid - pl0 * 9;
            const int pl = g * 16 + pl0;
            const float* v = part[0][pl];
            const int ch = 2 * a + 1;
            const int pair = (ch < 9) ? ch + 9 : ch - 9;
            const float score = 1.f / (1.f + expf(v[pair] - v[ch]));
            const float r0 = v[18 + 4 * a], r1 = v[19 + 4 * a];
            const float r2 = v[20 + 4 * a], r3 = v[21 + 4 * a];
            const float wb = WBASE[a], hb = HBASE[a];
            const int p = m0 + pl;
            const int h = p >> 7, w = p & 127;
            float* o = out + (p * 9 + a) * 5;
            o[0] = h * 16.f + wb * r0;
            o[1] = w * 16.f + hb * r1;
            o[2] = wb + expf(r2);
            o[3] = hb + expf(r3);
            o[4] = score;
        }
    }
}

extern "C" void kernel_launch(void* const* d_in, const int* in_sizes, int n_in,
                              void* d_out, int out_size, void* d_ws, size_t ws_size,
                              hipStream_t stream) {
    const float* x      = (const float*)d_in[0];
    const float* base_w = (const float*)d_in[1];
    const float* base_b = (const float*)d_in[2];
    const float* cls_w  = (const float*)d_in[3];
    const float* cls_b  = (const float*)d_in[4];
    const float* reg_w  = (const float*)d_in[5];
    const float* reg_b  = (const float*)d_in[6];
    float* out = (float*)d_out;

    char* ws = (char*)d_ws;
    u16* xpad = (u16*)ws;                                   // 34,611,200 B
    u16* wt   = (u16*)(ws + 34611200);                      //  9,437,184 B
    u16* wc   = (u16*)(ws + 34611200 + 9437184);            //     65,536 B
    u16* rpn  = (u16*)(ws + 34611200 + 9437184 + 65536);    // 16,777,216 B

    prep_all<<<2946, 256, 0, stream>>>(x, base_w, cls_w, reg_w, xpad, wt, wc);
    gemm_conv<<<512, 256, 0, stream>>>(xpad, wt, base_b, rpn);
    stage23<<<512, 256, 0, stream>>>(rpn, wc, cls_b, reg_b, out);
}